// Round 2
// baseline (7296.832 us; speedup 1.0000x reference)
//
#include <hip/hip_runtime.h>
#include <math.h>

static constexpr int NR = 4096;   // N rows
static constexpr int DD = 512;    // feature dim

// ---------------------------------------------------------------------------
// Templated fp32 tiled GEMM.
//   C[i,j] = f( sum_k opA(i,k) * (ks ? ks[k] : 1) * opB(k,j) )
//   TA: A stored [K,M] row-major (access A[k*lda+i]); else [M,K]
//   TB: B stored [N,K] row-major (access B[j*ldb+k]); else [K,N]
//   mode 0: C = acc
//   mode 1: C = exp(escale * acc)
//   mode 2: C += 1e-4f * acc
// All dims assumed multiples of 64 (M,N) / 32 (K) — true for this problem.
// ---------------------------------------------------------------------------
template<bool TA, bool TB>
__global__ __launch_bounds__(256)
void gemm_kernel(int M, int N, int K,
                 const float* __restrict__ A, int lda,
                 const float* __restrict__ B, int ldb,
                 float* __restrict__ C, int ldc,
                 const float* __restrict__ ks,
                 int mode, float escale)
{
    constexpr int BM = 64, BN = 64, BK = 32;
    __shared__ float As[BK][BM + 4];
    __shared__ float Bs[BK][BN + 4];
    const int bm = blockIdx.y * BM;
    const int bn = blockIdx.x * BN;
    const int tid = threadIdx.x;
    const int tx = tid & 15;       // 16 cols of threads
    const int ty = tid >> 4;       // 16 rows of threads
    float acc[4][4] = {};

    for (int k0 = 0; k0 < K; k0 += BK) {
        // ---- load A tile (with optional k-scale) ----
        #pragma unroll
        for (int l0 = 0; l0 < BM * BK; l0 += 256) {
            const int l = l0 + tid;
            int m, k;
            if (!TA) { k = l & (BK - 1); m = l / BK; }   // coalesced along k
            else     { m = l & (BM - 1); k = l / BM; }   // coalesced along m
            float a = TA ? A[(size_t)(k0 + k) * lda + (bm + m)]
                         : A[(size_t)(bm + m) * lda + (k0 + k)];
            if (ks) a *= ks[k0 + k];
            As[k][m] = a;
        }
        // ---- load B tile ----
        #pragma unroll
        for (int l0 = 0; l0 < BN * BK; l0 += 256) {
            const int l = l0 + tid;
            int n, k;
            if (!TB) { n = l & (BN - 1); k = l / BN; }   // coalesced along n
            else     { k = l & (BK - 1); n = l / BK; }   // coalesced along k
            Bs[k][n] = TB ? B[(size_t)(bn + n) * ldb + (k0 + k)]
                          : B[(size_t)(k0 + k) * ldb + (bn + n)];
        }
        __syncthreads();

        #pragma unroll
        for (int kk = 0; kk < BK; ++kk) {
            float a[4], b[4];
            #pragma unroll
            for (int i = 0; i < 4; ++i) a[i] = As[kk][ty * 4 + i];
            #pragma unroll
            for (int j = 0; j < 4; ++j) b[j] = Bs[kk][tx * 4 + j];
            #pragma unroll
            for (int i = 0; i < 4; ++i)
                #pragma unroll
                for (int j = 0; j < 4; ++j)
                    acc[i][j] = fmaf(a[i], b[j], acc[i][j]);
        }
        __syncthreads();
    }

    #pragma unroll
    for (int i = 0; i < 4; ++i) {
        const int row = bm + ty * 4 + i;
        #pragma unroll
        for (int j = 0; j < 4; ++j) {
            const int col = bn + tx * 4 + j;
            const size_t idx = (size_t)row * ldc + col;
            const float vacc = acc[i][j];
            if (mode == 0)      C[idx] = vacc;
            else if (mode == 1) C[idx] = __expf(escale * vacc);
            else                C[idx] += 1e-4f * vacc;
        }
    }
}

// u[i] = 1 / sum_j K[i,j] * v[j]      (one wave per row)
__global__ __launch_bounds__(256)
void rowmv_recip(const float* __restrict__ Kb, const float* __restrict__ v,
                 float* __restrict__ u)
{
    const int row  = blockIdx.x * (blockDim.x >> 6) + (threadIdx.x >> 6);
    const int lane = threadIdx.x & 63;
    const float* Krow = Kb + (size_t)row * NR;
    float s = 0.f;
    for (int j = lane; j < NR; j += 64) s += Krow[j] * v[j];
    #pragma unroll
    for (int off = 32; off; off >>= 1) s += __shfl_down(s, off);
    if (lane == 0) u[row] = 1.0f / s;
}

// tmp[j] += sum_{i in band} K[i,j] * u[i]   (banded, atomic accumulate)
__global__ __launch_bounds__(256)
void colmv_partial(const float* __restrict__ Kb, const float* __restrict__ u,
                   float* __restrict__ tmp, int rowsPerBand)
{
    const int j  = blockIdx.x * blockDim.x + threadIdx.x;
    const int i0 = blockIdx.y * rowsPerBand;
    float s = 0.f;
    for (int i = i0; i < i0 + rowsPerBand; ++i)
        s += Kb[(size_t)i * NR + j] * u[i];
    atomicAdd(&tmp[j], s);
}

__global__ void recip_kernel(const float* __restrict__ in, float* __restrict__ out, int n)
{
    const int i = blockIdx.x * blockDim.x + threadIdx.x;
    if (i < n) out[i] = 1.0f / in[i];
}

__global__ void fill_kernel(float* __restrict__ p, int n, float val)
{
    const int i = blockIdx.x * blockDim.x + threadIdx.x;
    if (i < n) p[i] = val;
}

__global__ void init_eye_kernel(float* __restrict__ A)   // A = I (DD x DD)
{
    const int i = blockIdx.x * blockDim.x + threadIdx.x;
    if (i < DD * DD) A[i] = (i / DD == i % DD) ? 1.0f : 0.0f;
}

// loss_i = log( sum_j exp(u_i K_ij v_j) ) - u_i K[i,y_i] v[y_i];  out = mean_i loss_i
__global__ __launch_bounds__(256)
void loss_kernel(const float* __restrict__ Kb, const float* __restrict__ u,
                 const float* __restrict__ v, const int* __restrict__ labels,
                 float* __restrict__ out)
{
    const int row  = blockIdx.x * (blockDim.x >> 6) + (threadIdx.x >> 6);
    const int lane = threadIdx.x & 63;
    const float* Krow = Kb + (size_t)row * NR;
    const float ui = u[row];
    float s = 0.f;
    for (int j = lane; j < NR; j += 64) s += __expf(ui * Krow[j] * v[j]);
    #pragma unroll
    for (int off = 32; off; off >>= 1) s += __shfl_down(s, off);
    if (lane == 0) {
        const int y = labels[row];
        const float py = ui * Krow[y] * v[y];
        atomicAdd(out, (logf(s) - py) * (1.0f / NR));
    }
}

extern "C" void kernel_launch(void* const* d_in, const int* in_sizes, int n_in,
                              void* d_out, int out_size, void* d_ws, size_t ws_size,
                              hipStream_t stream)
{
    const float* img    = (const float*)d_in[0];   // [4096,512]
    const float* txt    = (const float*)d_in[1];   // [4096,512]
    const int*   labels = (const int*)d_in[2];     // [4096]
    float* out = (float*)d_out;

    char* ws = (char*)d_ws;
    float* Kbuf = (float*)(ws);                                     // 4096*4096 f32 = 64 MiB
    float* NB   = (float*)(ws + ((size_t)64 << 20));                // 4096*512  f32 =  8 MiB
    float* Amat = (float*)(ws + ((size_t)72 << 20));                // 512*512   f32 =  1 MiB
    float* u    = (float*)(ws + ((size_t)73 << 20));                // 4096 f32
    float* v    = (float*)(ws + ((size_t)73 << 20) + (64 << 10));   // 4096 f32
    float* tmp  = (float*)(ws + ((size_t)73 << 20) + (128 << 10));  // 4096 f32

    const dim3 blk(256);
    const dim3 gridNN(NR / 64, NR / 64);   // 4096x4096 output
    const dim3 gridND(DD / 64, NR / 64);   // 4096x512 output
    const dim3 gridDD(DD / 64, DD / 64);   // 512x512 output

    // K = exp(100 * img @ txt^T)  == unnormalized softmax numerators of P0
    gemm_kernel<false, true><<<gridNN, blk, 0, stream>>>(
        NR, NR, DD, img, DD, txt, DD, Kbuf, NR, nullptr, 1, 100.0f);
    // P0 = diag(u) K diag(v) with v = 1, u = 1/rowsum  (exact row softmax)
    fill_kernel<<<16, 256, 0, stream>>>(v, NR, 1.0f);
    rowmv_recip<<<NR / 4, blk, 0, stream>>>(Kbuf, v, u);
    init_eye_kernel<<<(DD * DD) / 256, 256, 0, stream>>>(Amat);

    for (int it = 0; it < 5; ++it) {
        // NB = K @ (v .* txt)                       [4096,512], K-dim 4096
        gemm_kernel<false, false><<<gridND, blk, 0, stream>>>(
            NR, DD, NR, Kbuf, NR, txt, DD, NB, DD, v, 0, 0.0f);
        // Amat += 1e-4 * (u .* img)^T @ NB          [512,512], K-dim 4096
        gemm_kernel<true, false><<<gridDD, blk, 0, stream>>>(
            DD, DD, NR, img, DD, NB, DD, Amat, DD, u, 2, 0.0f);
        // NB = img @ Amat                           [4096,512], K-dim 512
        gemm_kernel<false, false><<<gridND, blk, 0, stream>>>(
            NR, DD, DD, img, DD, Amat, DD, NB, DD, nullptr, 0, 0.0f);
        // K = exp(-(NB @ txt^T))                    [4096,4096], K-dim 512
        gemm_kernel<false, true><<<gridNN, blk, 0, stream>>>(
            NR, NR, DD, NB, DD, txt, DD, Kbuf, NR, nullptr, 1, -1.0f);
        // Sinkhorn: 5 x { row-normalize (u-step); col-normalize (v-step) }
        fill_kernel<<<16, 256, 0, stream>>>(v, NR, 1.0f);
        for (int t = 0; t < 5; ++t) {
            rowmv_recip<<<NR / 4, blk, 0, stream>>>(Kbuf, v, u);
            hipMemsetAsync(tmp, 0, NR * sizeof(float), stream);
            colmv_partial<<<dim3(NR / 256, 64), blk, 0, stream>>>(Kbuf, u, tmp, NR / 64);
            recip_kernel<<<16, 256, 0, stream>>>(tmp, v, NR);
        }
    }

    // loss = mean_i [ logsumexp_j(P_ij) - P[i, y_i] ],  P = diag(u) K diag(v)
    hipMemsetAsync(out, 0, sizeof(float), stream);
    loss_kernel<<<NR / 4, blk, 0, stream>>>(Kbuf, u, v, labels, out);
}

// Round 4
// 3324.208 us; speedup vs baseline: 2.1951x; 2.1951x over previous
//
#include <hip/hip_runtime.h>
#include <math.h>

static constexpr int NR = 4096;   // N rows
static constexpr int DD = 512;    // feature dim

typedef __attribute__((ext_vector_type(8))) short short8v;
typedef __attribute__((ext_vector_type(4))) float floatx4;

__device__ __forceinline__ unsigned short f2bf(float f) {
    union { float f; unsigned u; } c; c.f = f;
    unsigned r = c.u + 0x7fffu + ((c.u >> 16) & 1u);   // RTNE
    return (unsigned short)(r >> 16);
}
__device__ __forceinline__ float bf2f(unsigned short h) {
    union { unsigned u; float f; } c; c.u = ((unsigned)h) << 16;
    return c.f;
}

#define GLOAD16(gp, lp) __builtin_amdgcn_global_load_lds(                       \
    (const __attribute__((address_space(1))) void*)(gp),                        \
    (__attribute__((address_space(3))) void*)(lp), 16, 0, 0)

// ---------------------------------------------------------------------------
// NT bf16 MFMA GEMM, 128x128 tile, 4 waves (2x2), wave tile 64x64 (4x4 frags
// of 16x16x32). A: [M, lda] bf16 row-major, B: [N, lda] bf16 row-major,
// C[m,n] = f( sum_k A[m,k] * B[n,k] ).  k range [z*KS, z*KS+KS), lda = full K.
// EPI 0: out bf16 = acc      EPI 1: out bf16 = exp(escale*acc)
// EPI 2: out f32 slice z: out[z*512*512 + m*ldc + n] = acc
// ---------------------------------------------------------------------------
template<int EPI>
__global__ __launch_bounds__(256)
void ntgemm(const unsigned short* __restrict__ A, const unsigned short* __restrict__ B,
            void* __restrict__ out, int lda, int KS, int ldc, float escale)
{
    __shared__ unsigned short As[128 * 32];   // [row][k] row-major, 8 KiB
    __shared__ unsigned short Bs[128 * 32];
    const int tid  = threadIdx.x;
    const int wave = tid >> 6, lane = tid & 63;
    const int bm = blockIdx.y * 128, bn = blockIdx.x * 128;
    const int wr = wave >> 1, wc = wave & 1;
    const int kBeg = blockIdx.z * KS;

    // staging: wave w covers rows [w*32, w*32+32) of the tile, 2 instrs (q=0,1)
    const int srow = wave * 32 + (lane >> 2);   // + q*16
    const int skb  = (lane & 3) * 8;            // k offset of this lane's 8 bf16
    const unsigned short* pA0 = A + (size_t)(bm + srow) * lda + kBeg + skb;
    const unsigned short* pA1 = pA0 + (size_t)16 * lda;
    const unsigned short* pB0 = B + (size_t)(bn + srow) * lda + kBeg + skb;
    const unsigned short* pB1 = pB0 + (size_t)16 * lda;
    unsigned short* lA0 = &As[wave * 1024];
    unsigned short* lA1 = &As[wave * 1024 + 512];
    unsigned short* lB0 = &Bs[wave * 1024];
    unsigned short* lB1 = &Bs[wave * 1024 + 512];

    floatx4 acc[4][4];
    #pragma unroll
    for (int i = 0; i < 4; ++i)
        #pragma unroll
        for (int j = 0; j < 4; ++j)
            acc[i][j] = (floatx4){0.f, 0.f, 0.f, 0.f};

    const int fr = lane & 15;           // A row / B col within 16
    const int kg = (lane >> 4) * 8;     // k group offset

    for (int k0 = 0; k0 < KS; k0 += 32) {
        GLOAD16(pA0 + k0, lA0);
        GLOAD16(pA1 + k0, lA1);
        GLOAD16(pB0 + k0, lB0);
        GLOAD16(pB1 + k0, lB1);
        __syncthreads();   // drains vmcnt + lgkmcnt before barrier

        short8v a[4], b[4];
        #pragma unroll
        for (int i = 0; i < 4; ++i)
            a[i] = *(const short8v*)&As[(wr * 64 + i * 16 + fr) * 32 + kg];
        #pragma unroll
        for (int j = 0; j < 4; ++j)
            b[j] = *(const short8v*)&Bs[(wc * 64 + j * 16 + fr) * 32 + kg];
        #pragma unroll
        for (int i = 0; i < 4; ++i)
            #pragma unroll
            for (int j = 0; j < 4; ++j)
                acc[i][j] = __builtin_amdgcn_mfma_f32_16x16x32_bf16(a[i], b[j], acc[i][j], 0, 0, 0);
        __syncthreads();
    }

    // epilogue: D[row=(lane>>4)*4+r][col=lane&15]  (m89-verified layout)
    const int r0 = (lane >> 4) * 4;
    #pragma unroll
    for (int i = 0; i < 4; ++i)
        #pragma unroll
        for (int j = 0; j < 4; ++j)
            #pragma unroll
            for (int r = 0; r < 4; ++r) {
                const int m = bm + wr * 64 + i * 16 + r0 + r;
                const int n = bn + wc * 64 + j * 16 + fr;
                float x = acc[i][j][r];
                if (EPI == 1) x = __expf(escale * x);
                if (EPI <= 1) ((unsigned short*)out)[(size_t)m * ldc + n] = f2bf(x);
                else ((float*)out)[(size_t)blockIdx.z * (512 * 512) + (size_t)m * ldc + n] = x;
            }
}

// out[i] = bf16(in[i]), processed 4-wide
__global__ void convert_bf16(const float* __restrict__ in, unsigned short* __restrict__ out, int n4)
{
    const int i = blockIdx.x * 256 + threadIdx.x;
    if (i < n4) {
        const float4 v = ((const float4*)in)[i];
        ushort4 o;
        o.x = f2bf(v.x); o.y = f2bf(v.y); o.z = f2bf(v.z); o.w = f2bf(v.w);
        ((ushort4*)out)[i] = o;
    }
}

// XT[d][i] = bf16( s[i] * X[i][d] ),  X: [NR, DD] f32, XT: [DD, NR] bf16
__global__ __launch_bounds__(256)
void scale_transpose(const float* __restrict__ X, const float* __restrict__ s,
                     unsigned short* __restrict__ XT)
{
    __shared__ float tile[64][65];
    const int i0 = blockIdx.x * 64;   // row block (i)
    const int d0 = blockIdx.y * 64;   // col block (d)
    const int t = threadIdx.x, c = t & 63, r4 = t >> 6;
    #pragma unroll
    for (int rr = 0; rr < 64; rr += 4) {
        const int i = i0 + rr + r4;
        tile[rr + r4][c] = X[(size_t)i * DD + d0 + c] * s[i];
    }
    __syncthreads();
    #pragma unroll
    for (int dd = 0; dd < 64; dd += 4) {
        const int d = dd + r4;
        XT[(size_t)(d0 + d) * NR + i0 + c] = f2bf(tile[c][d]);
    }
}

// Amat_f32[e][d] += 1e-4 * sum_z Dacc[z][e][d];  AmatT_b[d][e] = bf16(Amat_f32[e][d])
__global__ __launch_bounds__(256)
void amat_update(const float* __restrict__ Dacc, float* __restrict__ Af,
                 unsigned short* __restrict__ ATb)
{
    __shared__ float tile[64][65];
    const int e0 = blockIdx.x * 64, d0 = blockIdx.y * 64;
    const int t = threadIdx.x, c = t & 63, r4 = t >> 6;
    #pragma unroll
    for (int rr = 0; rr < 64; rr += 4) {
        const int e = e0 + rr + r4;
        const size_t idx = (size_t)e * DD + d0 + c;
        float ssum = 0.f;
        #pragma unroll
        for (int z = 0; z < 8; ++z) ssum += Dacc[(size_t)z * (512 * 512) + idx];
        const float nv = Af[idx] + 1e-4f * ssum;
        Af[idx] = nv;
        tile[rr + r4][c] = nv;
    }
    __syncthreads();
    #pragma unroll
    for (int dd = 0; dd < 64; dd += 4) {
        const int d = dd + r4;
        ATb[(size_t)(d0 + d) * DD + e0 + c] = f2bf(tile[c][d]);
    }
}

__global__ void init_amat(float* __restrict__ Af)
{
    const int i = blockIdx.x * 256 + threadIdx.x;
    if (i < DD * DD) Af[i] = (i / DD == i % DD) ? 1.0f : 0.0f;
}

__global__ void fill_kernel(float* __restrict__ p, int n, float val)
{
    const int i = blockIdx.x * 256 + threadIdx.x;
    if (i < n) p[i] = val;
}

// u[row] = 1 / sum_j K[row][j] * v[j]   (bf16 K, wave per row)
__global__ __launch_bounds__(256)
void rowmv_recip_b(const unsigned short* __restrict__ Kb, const float* __restrict__ v,
                   float* __restrict__ u)
{
    const int row = blockIdx.x * 4 + (threadIdx.x >> 6);
    const int lane = threadIdx.x & 63;
    const unsigned short* Kr = Kb + (size_t)row * NR;
    float s = 0.f;
    #pragma unroll
    for (int it = 0; it < 8; ++it) {
        const int j = it * 512 + lane * 8;
        const short8v kv = *(const short8v*)&Kr[j];
        const float4 va = *(const float4*)&v[j];
        const float4 vb = *(const float4*)&v[j + 4];
        s += bf2f((unsigned short)kv[0]) * va.x + bf2f((unsigned short)kv[1]) * va.y
           + bf2f((unsigned short)kv[2]) * va.z + bf2f((unsigned short)kv[3]) * va.w
           + bf2f((unsigned short)kv[4]) * vb.x + bf2f((unsigned short)kv[5]) * vb.y
           + bf2f((unsigned short)kv[6]) * vb.z + bf2f((unsigned short)kv[7]) * vb.w;
    }
    #pragma unroll
    for (int off = 32; off; off >>= 1) s += __shfl_xor(s, off);
    if (lane == 0) u[row] = 1.0f / s;
}

// Fused sinkhorn step (band of 16 rows per block):
//  phase1: u[i] = 1/sum_j K[i][j]*v[j]   phase2: tmp[j] += sum_band u[i]*K[i][j]
__global__ __launch_bounds__(256)
void fused_uv(const unsigned short* __restrict__ Kb, const float* __restrict__ v,
              float* __restrict__ u, float* __restrict__ tmp)
{
    __shared__ float uL[16];
    const int i0 = blockIdx.x * 16;
    const int wave = threadIdx.x >> 6, lane = threadIdx.x & 63;
    #pragma unroll
    for (int rr = 0; rr < 4; ++rr) {
        const int row = i0 + wave * 4 + rr;
        const unsigned short* Kr = Kb + (size_t)row * NR;
        float s = 0.f;
        #pragma unroll
        for (int it = 0; it < 8; ++it) {
            const int j = it * 512 + lane * 8;
            const short8v kv = *(const short8v*)&Kr[j];
            const float4 va = *(const float4*)&v[j];
            const float4 vb = *(const float4*)&v[j + 4];
            s += bf2f((unsigned short)kv[0]) * va.x + bf2f((unsigned short)kv[1]) * va.y
               + bf2f((unsigned short)kv[2]) * va.z + bf2f((unsigned short)kv[3]) * va.w
               + bf2f((unsigned short)kv[4]) * vb.x + bf2f((unsigned short)kv[5]) * vb.y
               + bf2f((unsigned short)kv[6]) * vb.z + bf2f((unsigned short)kv[7]) * vb.w;
        }
        #pragma unroll
        for (int off = 32; off; off >>= 1) s += __shfl_xor(s, off);
        if (lane == 0) {
            const float uu = 1.0f / s;
            uL[wave * 4 + rr] = uu;
            u[row] = uu;
        }
    }
    __syncthreads();
    float ul[16];
    #pragma unroll
    for (int r = 0; r < 16; ++r) ul[r] = uL[r];
    const int t = threadIdx.x;
    #pragma unroll
    for (int cb = 0; cb < 2; ++cb) {
        const int col = cb * 2048 + t * 8;
        float a8[8] = {0.f, 0.f, 0.f, 0.f, 0.f, 0.f, 0.f, 0.f};
        #pragma unroll
        for (int r = 0; r < 16; ++r) {
            const short8v kv = *(const short8v*)&Kb[(size_t)(i0 + r) * NR + col];
            const float uu = ul[r];
            a8[0] += uu * bf2f((unsigned short)kv[0]); a8[1] += uu * bf2f((unsigned short)kv[1]);
            a8[2] += uu * bf2f((unsigned short)kv[2]); a8[3] += uu * bf2f((unsigned short)kv[3]);
            a8[4] += uu * bf2f((unsigned short)kv[4]); a8[5] += uu * bf2f((unsigned short)kv[5]);
            a8[6] += uu * bf2f((unsigned short)kv[6]); a8[7] += uu * bf2f((unsigned short)kv[7]);
        }
        #pragma unroll
        for (int e = 0; e < 8; ++e) atomicAdd(&tmp[col + e], a8[e]);
    }
}

__global__ void recip_zero(float* __restrict__ tmp, float* __restrict__ v)
{
    const int i = blockIdx.x * 256 + threadIdx.x;
    if (i < NR) { v[i] = 1.0f / tmp[i]; tmp[i] = 0.f; }
}

// loss_i = log(sum_j exp(u_i K_ij v_j)) - u_i K[i,y] v[y];  out = mean_i
__global__ __launch_bounds__(256)
void loss_b(const unsigned short* __restrict__ Kb, const float* __restrict__ u,
            const float* __restrict__ v, const int* __restrict__ labels,
            float* __restrict__ out)
{
    const int row = blockIdx.x * 4 + (threadIdx.x >> 6);
    const int lane = threadIdx.x & 63;
    const unsigned short* Kr = Kb + (size_t)row * NR;
    const float ui = u[row];
    float s = 0.f;
    #pragma unroll
    for (int it = 0; it < 8; ++it) {
        const int j = it * 512 + lane * 8;
        const short8v kv = *(const short8v*)&Kr[j];
        const float4 va = *(const float4*)&v[j];
        const float4 vb = *(const float4*)&v[j + 4];
        s += __expf(ui * bf2f((unsigned short)kv[0]) * va.x)
           + __expf(ui * bf2f((unsigned short)kv[1]) * va.y)
           + __expf(ui * bf2f((unsigned short)kv[2]) * va.z)
           + __expf(ui * bf2f((unsigned short)kv[3]) * va.w)
           + __expf(ui * bf2f((unsigned short)kv[4]) * vb.x)
           + __expf(ui * bf2f((unsigned short)kv[5]) * vb.y)
           + __expf(ui * bf2f((unsigned short)kv[6]) * vb.z)
           + __expf(ui * bf2f((unsigned short)kv[7]) * vb.w);
    }
    #pragma unroll
    for (int off = 32; off; off >>= 1) s += __shfl_xor(s, off);
    if (lane == 0) {
        const int y = labels[row];
        const float py = ui * bf2f(Kr[y]) * v[y];
        atomicAdd(out, (logf(s) - py) * (1.0f / NR));
    }
}

extern "C" void kernel_launch(void* const* d_in, const int* in_sizes, int n_in,
                              void* d_out, int out_size, void* d_ws, size_t ws_size,
                              hipStream_t stream)
{
    const float* img    = (const float*)d_in[0];   // [4096,512]
    const float* txt    = (const float*)d_in[1];   // [4096,512]
    const int*   labels = (const int*)d_in[2];     // [4096]
    float* out = (float*)d_out;

    char* ws = (char*)d_ws;
    unsigned short* K_b    = (unsigned short*)(ws);                        // 32 MiB
    unsigned short* img_b  = (unsigned short*)(ws + ((size_t)32 << 20));   //  4 MiB
    unsigned short* txt_b  = (unsigned short*)(ws + ((size_t)36 << 20));   //  4 MiB
    unsigned short* vtxtT  = (unsigned short*)(ws + ((size_t)40 << 20));   //  4 MiB [512,4096]
    unsigned short* uimgT  = (unsigned short*)(ws + ((size_t)44 << 20));   //  4 MiB [512,4096]
    unsigned short* NB2T   = (unsigned short*)(ws + ((size_t)48 << 20));   //  4 MiB [512,4096]
    unsigned short* NB_b   = (unsigned short*)(ws + ((size_t)52 << 20));   //  4 MiB [4096,512]
    unsigned short* AmatT  = (unsigned short*)(ws + ((size_t)56 << 20));   // 0.5 MiB [512,512]
    float* Amat_f          = (float*)(ws + ((size_t)57 << 20));            //  1 MiB
    float* Dacc            = (float*)(ws + ((size_t)58 << 20));            //  8 MiB (8 slices)
    float* u               = (float*)(ws + ((size_t)66 << 20));
    float* v               = (float*)(ws + ((size_t)66 << 20) + (16 << 10));
    float* tmp             = (float*)(ws + ((size_t)66 << 20) + (32 << 10));

    const dim3 blk(256);
    const dim3 gNN(32, 32);    // 4096x4096 out
    const dim3 gG2(32, 4);     // 512x4096 out
    const dim3 gG3(4, 4, 8);   // 512x512 out, split-K 8
    const dim3 gG4(4, 32);     // 4096x512 out
    const dim3 gST(64, 8);     // scale_transpose

    convert_bf16<<<2048, blk, 0, stream>>>(img, img_b, NR * DD / 4);
    convert_bf16<<<2048, blk, 0, stream>>>(txt, txt_b, NR * DD / 4);
    hipMemsetAsync(tmp, 0, NR * sizeof(float), stream);

    // K = exp(100 * img.txt^T)   (row-softmax numerators; shift by -100 is exact)
    ntgemm<1><<<gNN, blk, 0, stream>>>(img_b, txt_b, K_b, DD, DD, NR, 100.0f);
    fill_kernel<<<16, blk, 0, stream>>>(v, NR, 1.0f);
    rowmv_recip_b<<<NR / 4, blk, 0, stream>>>(K_b, v, u);   // u = 1/rowsum
    init_amat<<<DD * DD / 256, blk, 0, stream>>>(Amat_f);

    for (int it = 0; it < 5; ++it) {
        // vtxtT[d][j] = v[j]*txt[j][d];  uimgT[e][i] = u[i]*img[i][e]
        scale_transpose<<<gST, blk, 0, stream>>>(txt, v, vtxtT);
        // NB2T[d][i] = sum_j vtxtT[d][j] * K[i][j]      (= (K @ (v.txt))^T)
        ntgemm<0><<<gG2, blk, 0, stream>>>(vtxtT, K_b, NB2T, NR, NR, NR, 0.f);
        scale_transpose<<<gST, blk, 0, stream>>>(img, u, uimgT);
        // Dacc[z][e][d] = partial sum_i uimgT[e][i] * NB2T[d][i]
        ntgemm<2><<<gG3, blk, 0, stream>>>(uimgT, NB2T, Dacc, NR, NR / 8, DD, 0.f);
        // Amat += 1e-4 * sum_z Dacc;  AmatT = bf16(Amat^T)
        amat_update<<<dim3(8, 8), blk, 0, stream>>>(Dacc, Amat_f, AmatT);
        // NB[i][d] = sum_e img[i][e] * AmatT[d][e]      (= img @ Amat)
        ntgemm<0><<<gG4, blk, 0, stream>>>(img_b, AmatT, NB_b, DD, DD, DD, 0.f);
        // K = exp(-(NB @ txt^T))                        (= exp(C-1), exact)
        ntgemm<1><<<gNN, blk, 0, stream>>>(NB_b, txt_b, K_b, DD, DD, NR, -1.0f);
        // sinkhorn: 5 x { u = 1/(K v) ; v = 1/(K^T u) }
        fill_kernel<<<16, blk, 0, stream>>>(v, NR, 1.0f);
        for (int t = 0; t < 5; ++t) {
            fused_uv<<<NR / 16, blk, 0, stream>>>(K_b, v, u, tmp);
            recip_zero<<<16, blk, 0, stream>>>(tmp, v);
        }
    }

    hipMemsetAsync(out, 0, sizeof(float), stream);
    loss_b<<<NR / 4, blk, 0, stream>>>(K_b, u, v, labels, out);
}

// Round 7
// 2433.488 us; speedup vs baseline: 2.9985x; 1.3660x over previous
//
#include <hip/hip_runtime.h>
#include <math.h>

static constexpr int NR = 4096;   // N rows
static constexpr int DD = 512;    // feature dim

typedef __attribute__((ext_vector_type(8))) short short8v;
typedef __attribute__((ext_vector_type(4))) float floatx4;

__device__ __forceinline__ unsigned short f2bf(float f) {
    union { float f; unsigned u; } c; c.f = f;
    unsigned r = c.u + 0x7fffu + ((c.u >> 16) & 1u);   // RTNE
    return (unsigned short)(r >> 16);
}
__device__ __forceinline__ float bf2f(unsigned short h) {
    union { unsigned u; float f; } c; c.u = ((unsigned)h) << 16;
    return c.f;
}
__device__ __forceinline__ float blo(unsigned w) {
    union { unsigned u; float f; } c; c.u = w << 16; return c.f;
}
__device__ __forceinline__ float bhi(unsigned w) {
    union { unsigned u; float f; } c; c.u = w & 0xffff0000u; return c.f;
}

#define GLOAD16(gp, lp) __builtin_amdgcn_global_load_lds(                       \
    (const __attribute__((address_space(1))) void*)(gp),                        \
    (__attribute__((address_space(3))) void*)(lp), 16, 0, 0)

// ---------------------------------------------------------------------------
// NT bf16 MFMA GEMM (unchanged from round 2/4 — verified absmax 0.0).
// ---------------------------------------------------------------------------
template<int EPI>
__global__ __launch_bounds__(256)
void ntgemm(const unsigned short* __restrict__ A, const unsigned short* __restrict__ B,
            void* __restrict__ out, int lda, int KS, int ldc, float escale)
{
    __shared__ unsigned short As[128 * 32];
    __shared__ unsigned short Bs[128 * 32];
    const int tid  = threadIdx.x;
    const int wave = tid >> 6, lane = tid & 63;
    const int bm = blockIdx.y * 128, bn = blockIdx.x * 128;
    const int wr = wave >> 1, wc = wave & 1;
    const int kBeg = blockIdx.z * KS;

    const int srow = wave * 32 + (lane >> 2);
    const int skb  = (lane & 3) * 8;
    const unsigned short* pA0 = A + (size_t)(bm + srow) * lda + kBeg + skb;
    const unsigned short* pA1 = pA0 + (size_t)16 * lda;
    const unsigned short* pB0 = B + (size_t)(bn + srow) * lda + kBeg + skb;
    const unsigned short* pB1 = pB0 + (size_t)16 * lda;
    unsigned short* lA0 = &As[wave * 1024];
    unsigned short* lA1 = &As[wave * 1024 + 512];
    unsigned short* lB0 = &Bs[wave * 1024];
    unsigned short* lB1 = &Bs[wave * 1024 + 512];

    floatx4 acc[4][4];
    #pragma unroll
    for (int i = 0; i < 4; ++i)
        #pragma unroll
        for (int j = 0; j < 4; ++j)
            acc[i][j] = (floatx4){0.f, 0.f, 0.f, 0.f};

    const int fr = lane & 15;
    const int kg = (lane >> 4) * 8;

    for (int k0 = 0; k0 < KS; k0 += 32) {
        GLOAD16(pA0 + k0, lA0);
        GLOAD16(pA1 + k0, lA1);
        GLOAD16(pB0 + k0, lB0);
        GLOAD16(pB1 + k0, lB1);
        __syncthreads();

        short8v a[4], b[4];
        #pragma unroll
        for (int i = 0; i < 4; ++i)
            a[i] = *(const short8v*)&As[(wr * 64 + i * 16 + fr) * 32 + kg];
        #pragma unroll
        for (int j = 0; j < 4; ++j)
            b[j] = *(const short8v*)&Bs[(wc * 64 + j * 16 + fr) * 32 + kg];
        #pragma unroll
        for (int i = 0; i < 4; ++i)
            #pragma unroll
            for (int j = 0; j < 4; ++j)
                acc[i][j] = __builtin_amdgcn_mfma_f32_16x16x32_bf16(a[i], b[j], acc[i][j], 0, 0, 0);
        __syncthreads();
    }

    const int r0 = (lane >> 4) * 4;
    #pragma unroll
    for (int i = 0; i < 4; ++i)
        #pragma unroll
        for (int j = 0; j < 4; ++j)
            #pragma unroll
            for (int r = 0; r < 4; ++r) {
                const int m = bm + wr * 64 + i * 16 + r0 + r;
                const int n = bn + wc * 64 + j * 16 + fr;
                float x = acc[i][j][r];
                if (EPI == 1) x = __expf(escale * x);
                if (EPI <= 1) ((unsigned short*)out)[(size_t)m * ldc + n] = f2bf(x);
                else ((float*)out)[(size_t)blockIdx.z * (512 * 512) + (size_t)m * ldc + n] = x;
            }
}

__global__ void convert_bf16(const float* __restrict__ in, unsigned short* __restrict__ out, int n4)
{
    const int i = blockIdx.x * 256 + threadIdx.x;
    if (i < n4) {
        const float4 v = ((const float4*)in)[i];
        ushort4 o;
        o.x = f2bf(v.x); o.y = f2bf(v.y); o.z = f2bf(v.z); o.w = f2bf(v.w);
        ((ushort4*)out)[i] = o;
    }
}

// XT[d][i] = bf16( s[i] * X[i][d] )
__global__ __launch_bounds__(256)
void scale_transpose(const float* __restrict__ X, const float* __restrict__ s,
                     unsigned short* __restrict__ XT)
{
    __shared__ float tile[64][65];
    const int i0 = blockIdx.x * 64;
    const int d0 = blockIdx.y * 64;
    const int t = threadIdx.x, c = t & 63, r4 = t >> 6;
    #pragma unroll
    for (int rr = 0; rr < 64; rr += 4) {
        const int i = i0 + rr + r4;
        tile[rr + r4][c] = X[(size_t)i * DD + d0 + c] * s[i];
    }
    __syncthreads();
    #pragma unroll
    for (int dd = 0; dd < 64; dd += 4) {
        const int d = dd + r4;
        XT[(size_t)(d0 + d) * NR + i0 + c] = f2bf(tile[c][d]);
    }
}

__global__ __launch_bounds__(256)
void amat_update(const float* __restrict__ Dacc, float* __restrict__ Af,
                 unsigned short* __restrict__ ATb)
{
    __shared__ float tile[64][65];
    const int e0 = blockIdx.x * 64, d0 = blockIdx.y * 64;
    const int t = threadIdx.x, c = t & 63, r4 = t >> 6;
    #pragma unroll
    for (int rr = 0; rr < 64; rr += 4) {
        const int e = e0 + rr + r4;
        const size_t idx = (size_t)e * DD + d0 + c;
        float ssum = 0.f;
        #pragma unroll
        for (int z = 0; z < 8; ++z) ssum += Dacc[(size_t)z * (512 * 512) + idx];
        const float nv = Af[idx] + 1e-4f * ssum;
        Af[idx] = nv;
        tile[rr + r4][c] = nv;
    }
    __syncthreads();
    #pragma unroll
    for (int dd = 0; dd < 64; dd += 4) {
        const int d = dd + r4;
        ATb[(size_t)(d0 + d) * DD + e0 + c] = f2bf(tile[c][d]);
    }
}

__global__ void init_amat(float* __restrict__ Af)
{
    const int i = blockIdx.x * 256 + threadIdx.x;
    if (i < DD * DD) Af[i] = (i / DD == i % DD) ? 1.0f : 0.0f;
}

__global__ void fill_kernel(float* __restrict__ p, int n, float val)
{
    const int i = blockIdx.x * 256 + threadIdx.x;
    if (i < n) p[i] = val;
}

// u[row] = 1 / sum_j K[row][j] * v[j]   (initial softmax denominators)
__global__ __launch_bounds__(256)
void rowmv_recip_b(const unsigned short* __restrict__ Kb, const float* __restrict__ v,
                   float* __restrict__ u)
{
    const int row = blockIdx.x * 4 + (threadIdx.x >> 6);
    const int lane = threadIdx.x & 63;
    const unsigned short* Kr = Kb + (size_t)row * NR;
    float s = 0.f;
    #pragma unroll
    for (int it = 0; it < 8; ++it) {
        const int j = it * 512 + lane * 8;
        const uint4 kw = *(const uint4*)&Kr[j];
        const float4 va = *(const float4*)&v[j];
        const float4 vb = *(const float4*)&v[j + 4];
        s += blo(kw.x) * va.x + bhi(kw.x) * va.y + blo(kw.y) * va.z + bhi(kw.y) * va.w
           + blo(kw.z) * vb.x + bhi(kw.z) * vb.y + blo(kw.w) * vb.z + bhi(kw.w) * vb.w;
    }
    #pragma unroll
    for (int off = 32; off; off >>= 1) s += __shfl_xor(s, off);
    if (lane == 0) u[row] = 1.0f / s;
}

// ---------------------------------------------------------------------------
// Cooperative persistent Sinkhorn: 256 blocks, block b owns rows [16b,16b+16).
// K band (16 x 4096 bf16 = 128 KiB) lives in LDS, XOR-swizzled so all-lanes-
// same-row b128 chunk reads spread over all 8 bank groups.
// 5 x { u = 1/(K v)  [LDS-local];  v = 1/(K^T u)  [4 MB partial + grid bar] }.
// doLoss: fold the CE loss over P = diag(u) K diag(v) into the tail.
// ---------------------------------------------------------------------------
__device__ __forceinline__ int swz(int r, int c2) {   // byte offset into band
    return r * 8192 + (c2 ^ (((c2 >> 7) & 7) << 4));
}

__device__ __forceinline__ void grid_barrier(int* bar, int gen)
{
    __syncthreads();
    if (threadIdx.x == 0) {
        __threadfence();                       // release: flush block's writes
        atomicAdd(bar, 1);
        while (atomicAdd(bar, 0) < gen * 256)  // monotonic counter, no reset
            __builtin_amdgcn_s_sleep(8);
        __threadfence();                       // acquire: invalidate stale lines
    }
    __syncthreads();
}

__global__ __launch_bounds__(256, 1)
void sinkhorn5(const unsigned short* __restrict__ Kb,
               float* __restrict__ ug, float* __restrict__ vg,
               float* __restrict__ Pp, int* __restrict__ bar,
               const int* __restrict__ labels, float* __restrict__ out,
               int baseGen, int doLoss)
{
    __shared__ unsigned short Ks[16 * 4096];   // 128 KiB swizzled band
    __shared__ float red[4][16];
    __shared__ float uL[16];
    __shared__ float lossRed[16];

    const int b = blockIdx.x;
    const int t = threadIdx.x;
    const int wave = t >> 6, lane = t & 63;

    // ---- stage band: rows [16b, 16b+16) ----
    const char* gK = (const char*)(Kb + (size_t)b * 16 * NR);
    char* lK = (char*)Ks;
    #pragma unroll
    for (int l = 0; l < 32; ++l) {
        const int ci = l * 256 + t;           // 16B chunk id (8192 total)
        const int r  = ci >> 9;               // 512 chunks per row
        const int c2 = (ci & 511) * 16;       // byte offset within row
        const uint4 d = *(const uint4*)(gK + r * 8192 + c2);
        *(uint4*)(lK + swz(r, c2)) = d;
    }
    __syncthreads();

    // thread t owns cols [16t, 16t+16): precompute swizzled chunk offsets
    const int cb   = t * 32;                  // byte base of col chunk
    const int swc0 = cb ^ (((cb >> 7) & 7) << 4);
    const int cb1  = cb + 16;
    const int swc1 = cb1 ^ (((cb1 >> 7) & 7) << 4);

    float vr[16];
    #pragma unroll
    for (int c = 0; c < 16; ++c) vr[c] = 1.0f;

    for (int it = 0; it < 5; ++it) {
        // ---- u-phase: rowpart over own cols, then block-reduce per row ----
        float rp[16];
        #pragma unroll
        for (int r = 0; r < 16; ++r) {
            const uint4 A = *(const uint4*)(lK + r * 8192 + swc0);
            const uint4 B = *(const uint4*)(lK + r * 8192 + swc1);
            rp[r] = blo(A.x)*vr[0]  + bhi(A.x)*vr[1]  + blo(A.y)*vr[2]  + bhi(A.y)*vr[3]
                  + blo(A.z)*vr[4]  + bhi(A.z)*vr[5]  + blo(A.w)*vr[6]  + bhi(A.w)*vr[7]
                  + blo(B.x)*vr[8]  + bhi(B.x)*vr[9]  + blo(B.y)*vr[10] + bhi(B.y)*vr[11]
                  + blo(B.z)*vr[12] + bhi(B.z)*vr[13] + blo(B.w)*vr[14] + bhi(B.w)*vr[15];
        }
        #pragma unroll
        for (int r = 0; r < 16; ++r) {
            float s = rp[r];
            #pragma unroll
            for (int off = 32; off; off >>= 1) s += __shfl_xor(s, off);
            if (lane == 0) red[wave][r] = s;
        }
        __syncthreads();
        if (t < 16) uL[t] = 1.0f / (red[0][t] + red[1][t] + red[2][t] + red[3][t]);
        __syncthreads();

        // ---- v-phase: col partials over the block's 16 rows ----
        float cp[16];
        #pragma unroll
        for (int c = 0; c < 16; ++c) cp[c] = 0.f;
        #pragma unroll
        for (int r = 0; r < 16; ++r) {
            const float ur = uL[r];
            const uint4 A = *(const uint4*)(lK + r * 8192 + swc0);
            const uint4 B = *(const uint4*)(lK + r * 8192 + swc1);
            cp[0]  += ur * blo(A.x); cp[1]  += ur * bhi(A.x);
            cp[2]  += ur * blo(A.y); cp[3]  += ur * bhi(A.y);
            cp[4]  += ur * blo(A.z); cp[5]  += ur * bhi(A.z);
            cp[6]  += ur * blo(A.w); cp[7]  += ur * bhi(A.w);
            cp[8]  += ur * blo(B.x); cp[9]  += ur * bhi(B.x);
            cp[10] += ur * blo(B.y); cp[11] += ur * bhi(B.y);
            cp[12] += ur * blo(B.z); cp[13] += ur * bhi(B.z);
            cp[14] += ur * blo(B.w); cp[15] += ur * bhi(B.w);
        }
        {   // write partial row P[b][16t .. 16t+16)
            float4* pw = (float4*)(Pp + (size_t)b * NR + t * 16);
            pw[0] = make_float4(cp[0],  cp[1],  cp[2],  cp[3]);
            pw[1] = make_float4(cp[4],  cp[5],  cp[6],  cp[7]);
            pw[2] = make_float4(cp[8],  cp[9],  cp[10], cp[11]);
            pw[3] = make_float4(cp[12], cp[13], cp[14], cp[15]);
        }
        grid_barrier(bar, baseGen + it * 2 + 1);

        // ---- v-reduce: block b reduces cols [16b, 16b+16) over 256 partials
        {
            const float4* pr = (const float4*)(Pp + (size_t)t * NR + b * 16);
            const float4 q0 = pr[0], q1 = pr[1], q2 = pr[2], q3 = pr[3];
            float val[16] = { q0.x, q0.y, q0.z, q0.w, q1.x, q1.y, q1.z, q1.w,
                              q2.x, q2.y, q2.z, q2.w, q3.x, q3.y, q3.z, q3.w };
            #pragma unroll
            for (int c = 0; c < 16; ++c) {
                float s = val[c];
                #pragma unroll
                for (int off = 32; off; off >>= 1) s += __shfl_xor(s, off);
                if (lane == 0) red[wave][c] = s;
            }
            __syncthreads();
            if (t < 16)
                vg[b * 16 + t] = 1.0f / (red[0][t] + red[1][t] + red[2][t] + red[3][t]);
        }
        grid_barrier(bar, baseGen + it * 2 + 2);

        // ---- reload own v slice ----
        const float4* vv = (const float4*)(vg + t * 16);
        const float4 v0 = vv[0], v1 = vv[1], v2 = vv[2], v3 = vv[3];
        vr[0]=v0.x; vr[1]=v0.y; vr[2]=v0.z; vr[3]=v0.w;
        vr[4]=v1.x; vr[5]=v1.y; vr[6]=v1.z; vr[7]=v1.w;
        vr[8]=v2.x; vr[9]=v2.y; vr[10]=v2.z; vr[11]=v2.w;
        vr[12]=v3.x; vr[13]=v3.y; vr[14]=v3.z; vr[15]=v3.w;
    }

    // ---- publish final u ----
    if (t < 16) ug[b * 16 + t] = uL[t];

    if (doLoss) {
        // loss_i = log(sum_j exp(u_i K_ij v_j)) - u_i K[i,y] v[y]
        #pragma unroll
        for (int r = 0; r < 16; ++r) {
            const float ur = uL[r];
            const uint4 A = *(const uint4*)(lK + r * 8192 + swc0);
            const uint4 B = *(const uint4*)(lK + r * 8192 + swc1);
            float s = __expf(ur*blo(A.x)*vr[0])  + __expf(ur*bhi(A.x)*vr[1])
                    + __expf(ur*blo(A.y)*vr[2])  + __expf(ur*bhi(A.y)*vr[3])
                    + __expf(ur*blo(A.z)*vr[4])  + __expf(ur*bhi(A.z)*vr[5])
                    + __expf(ur*blo(A.w)*vr[6])  + __expf(ur*bhi(A.w)*vr[7])
                    + __expf(ur*blo(B.x)*vr[8])  + __expf(ur*bhi(B.x)*vr[9])
                    + __expf(ur*blo(B.y)*vr[10]) + __expf(ur*bhi(B.y)*vr[11])
                    + __expf(ur*blo(B.z)*vr[12]) + __expf(ur*bhi(B.z)*vr[13])
                    + __expf(ur*blo(B.w)*vr[14]) + __expf(ur*bhi(B.w)*vr[15]);
            #pragma unroll
            for (int off = 32; off; off >>= 1) s += __shfl_xor(s, off);
            if (lane == 0) red[wave][r] = s;
        }
        __syncthreads();
        if (t < 16) {
            const float s = red[0][t] + red[1][t] + red[2][t] + red[3][t];
            const int row = b * 16 + t;
            const int y = labels[row];
            const int c2 = y * 2;
            const unsigned short kv = *(const unsigned short*)(lK + swz(t, c2));
            const float py = uL[t] * bf2f(kv) * vg[y];
            lossRed[t] = logf(s) - py;
        }
        __syncthreads();
        if (t == 0) {
            float s = 0.f;
            #pragma unroll
            for (int r = 0; r < 16; ++r) s += lossRed[r];
            atomicAdd(out, s * (1.0f / NR));
        }
    }
}

extern "C" void kernel_launch(void* const* d_in, const int* in_sizes, int n_in,
                              void* d_out, int out_size, void* d_ws, size_t ws_size,
                              hipStream_t stream)
{
    const float* img    = (const float*)d_in[0];   // [4096,512]
    const float* txt    = (const float*)d_in[1];   // [4096,512]
    const int*   labels = (const int*)d_in[2];     // [4096]
    float* out = (float*)d_out;

    char* ws = (char*)d_ws;
    unsigned short* K_b    = (unsigned short*)(ws);                        // 32 MiB
    unsigned short* img_b  = (unsigned short*)(ws + ((size_t)32 << 20));   //  4 MiB
    unsigned short* txt_b  = (unsigned short*)(ws + ((size_t)36 << 20));   //  4 MiB
    unsigned short* vtxtT  = (unsigned short*)(ws + ((size_t)40 << 20));   //  4 MiB
    unsigned short* uimgT  = (unsigned short*)(ws + ((size_t)44 << 20));   //  4 MiB
    unsigned short* NB2T   = (unsigned short*)(ws + ((size_t)48 << 20));   //  4 MiB
    unsigned short* NB_b   = (unsigned short*)(ws + ((size_t)52 << 20));   //  4 MiB
    unsigned short* AmatT  = (unsigned short*)(ws + ((size_t)56 << 20));   // 0.5 MiB
    float* Amat_f          = (float*)(ws + ((size_t)57 << 20));            //  1 MiB
    float* Dacc            = (float*)(ws + ((size_t)58 << 20));            //  8 MiB
    float* Pbuf            = Dacc;   // alias: Dacc dead once amat_update ran
    float* u               = (float*)(ws + ((size_t)66 << 20));
    float* v               = (float*)(ws + ((size_t)66 << 20) + (16 << 10));
    int*   bar             = (int*)  (ws + ((size_t)66 << 20) + (32 << 10));

    const dim3 blk(256);
    const dim3 gNN(32, 32);
    const dim3 gG2(32, 4);
    const dim3 gG3(4, 4, 8);
    const dim3 gG4(4, 32);
    const dim3 gST(64, 8);

    convert_bf16<<<2048, blk, 0, stream>>>(img, img_b, NR * DD / 4);
    convert_bf16<<<2048, blk, 0, stream>>>(txt, txt_b, NR * DD / 4);
    hipMemsetAsync(bar, 0, sizeof(int), stream);
    hipMemsetAsync(out, 0, sizeof(float), stream);

    // K = exp(100 * img.txt^T); u = 1/rowsum (exact row softmax); A = I
    ntgemm<1><<<gNN, blk, 0, stream>>>(img_b, txt_b, K_b, DD, DD, NR, 100.0f);
    fill_kernel<<<16, blk, 0, stream>>>(v, NR, 1.0f);
    rowmv_recip_b<<<NR / 4, blk, 0, stream>>>(K_b, v, u);
    init_amat<<<DD * DD / 256, blk, 0, stream>>>(Amat_f);

    for (int it = 0; it < 5; ++it) {
        scale_transpose<<<gST, blk, 0, stream>>>(txt, v, vtxtT);
        ntgemm<0><<<gG2, blk, 0, stream>>>(vtxtT, K_b, NB2T, NR, NR, NR, 0.f);
        scale_transpose<<<gST, blk, 0, stream>>>(img, u, uimgT);
        ntgemm<2><<<gG3, blk, 0, stream>>>(uimgT, NB2T, Dacc, NR, NR / 8, DD, 0.f);
        amat_update<<<dim3(8, 8), blk, 0, stream>>>(Dacc, Amat_f, AmatT);
        ntgemm<0><<<gG4, blk, 0, stream>>>(img_b, AmatT, NB_b, DD, DD, DD, 0.f);
        ntgemm<1><<<gNN, blk, 0, stream>>>(NB_b, txt_b, K_b, DD, DD, NR, -1.0f);

        // cooperative persistent sinkhorn (5 inner iters; loss folded in last)
        int baseGen = it * 10;
        int doLoss  = (it == 4) ? 1 : 0;
        const unsigned short* Kc = K_b;
        const int* lab = labels;
        void* args[] = { (void*)&Kc, (void*)&u, (void*)&v, (void*)&Pbuf,
                         (void*)&bar, (void*)&lab, (void*)&out,
                         (void*)&baseGen, (void*)&doLoss };
        hipLaunchCooperativeKernel((void*)sinkhorn5, dim3(256), blk, args, 0, stream);
    }
}